// Round 1
// baseline (247.076 us; speedup 1.0000x reference)
//
#include <hip/hip_runtime.h>
#include <hip/hip_bf16.h>

// MHA: B=4 T=2048 C=1024 H=16 D=64, fp32 in/out, bf16 MFMA internally.
// R9: QKV GEMM was 75.8us @ 680 TF = the 2-barrier-structure plateau
//     (MfmaUtil 27%). Replace with 256x256 8-wave 4-phase/K-tile kernel
//     (T3+T4 counted vmcnt(6), T5 setprio, T2 swizzle carried over, T1
//     XCD chunking). Stage/read schedule proven WAR/RAW-safe:
//       reads:  ph0 = all B (reg-cached) + A m0-1; ph1 = A m2-3;
//               ph2 = A m4-7; ph3 = none.
//       stages: ph0 -> (t+1)A1 (other buf); ph1 -> (t+2)B0;
//               ph2 -> (t+2)B1; ph3 -> (t+2)A0 (same buf, regions
//               read-complete in a prior, barrier-separated phase).
//       vmcnt(6) at ph3 => tile t+1 fully landed; drain 0 on last 2 iters.
//     Proj GEMM + attention unchanged from R8.

typedef unsigned short u16;
typedef __bf16 bf16_t;
typedef bf16_t bf16x8 __attribute__((ext_vector_type(8)));
typedef float f32x4 __attribute__((ext_vector_type(4)));
typedef u16 u16x8 __attribute__((ext_vector_type(8)));
typedef const __attribute__((address_space(1))) void* as1cv;
typedef __attribute__((address_space(3))) void* as3v;

#define BB 4
#define TT 2048
#define CC 1024
#define HH 16
#define DD 64

static __device__ __forceinline__ u16 f2bf(float f) {
  union { float f; unsigned int u; } x; x.f = f;
  unsigned int u = x.u;
  u += 0x7fff + ((u >> 16) & 1);   // round-to-nearest-even
  return (u16)(u >> 16);
}

// pack two f32 -> two bf16 (truncation) in one v_perm_b32
static __device__ __forceinline__ unsigned int pack2(float lo, float hi) {
  return __builtin_amdgcn_perm(__float_as_uint(hi), __float_as_uint(lo),
                               0x07060302u);
}

// ---------------- fp32 -> bf16 row cast (x) --------------------------------
__global__ __launch_bounds__(256) void cast_f32_bf16(
    const float* __restrict__ in, u16* __restrict__ out) {
  int i = (blockIdx.x * 256 + threadIdx.x) * 4;
  float4 v = *(const float4*)(in + i);
  ushort4 o;
  o.x = f2bf(v.x); o.y = f2bf(v.y); o.z = f2bf(v.z); o.w = f2bf(v.w);
  *(ushort4*)(out + i) = o;
}

// ---------------- transpose + cast fp32[K][N] -> bf16[N][K] ----------------
__global__ __launch_bounds__(256) void transpose_cast(
    const float* __restrict__ in, u16* __restrict__ out, int K, int N) {
  __shared__ float tile[32][33];
  int n0 = blockIdx.x * 32, k0 = blockIdx.y * 32;
  int tx = threadIdx.x & 31, ty = threadIdx.x >> 5;  // 32 x 8
#pragma unroll
  for (int i = 0; i < 32; i += 8)
    tile[ty + i][tx] = in[(size_t)(k0 + ty + i) * N + n0 + tx];
  __syncthreads();
#pragma unroll
  for (int i = 0; i < 32; i += 8)
    out[(size_t)(n0 + ty + i) * K + k0 + tx] = f2bf(tile[tx][ty + i]);
}

// ---------------- QKV GEMM: 256x256 tile, 8 waves, 4-phase K-loop ----------
// C[8192][3072] = A[8192][1024] * Bt[3072][1024]^T, scattered to q/k/vt.
// LDS: 2 x (A 256x64 + B 256x64) bf16 = 128 KiB. Swizzle: 16B slot =
// blk ^ (row & 7) (pre-swizzled global source, linear gload_lds dest).
__global__ __launch_bounds__(512, 2) void gemm_qkv256(
    const u16* __restrict__ A, const u16* __restrict__ Bt,
    const float* __restrict__ bias,
    u16* __restrict__ qb, u16* __restrict__ kb, u16* __restrict__ vt) {
  constexpr int K = 1024;
  constexpr int NT = 16;                     // K / 64
  __shared__ u16 As[2][256][64];             // 64 KB
  __shared__ u16 Bs[2][256][64];             // 64 KB
  const int tid = threadIdx.x;
  const int lane = tid & 63, wave = tid >> 6;
  const int quad = lane >> 4, l16 = lane & 15;
  const int wr = wave >> 2, wc = wave & 3;   // 2x4 waves, 128x64 out each
  const int rsw = l16 & 7;                   // fragment-read swizzle
  const int srow8 = tid >> 3;                // 0..63: row in 64-row stripe
  const int sblk = (lane & 7) ^ (lane >> 3); // pre-swizzled source blk

  // XCD-aware chunking: 384 blocks -> 8 chunks of 48 = 8mi x 6ni rects
  const int id = blockIdx.x;
  const int ch = id & 7, w = id >> 3;
  const int mi = (ch & 3) * 8 + w / 6;
  const int ni = (ch >> 2) * 6 + w % 6;
  const int m0 = mi * 256, n0 = ni * 256;

  const u16* Ab = A + (size_t)(m0 + srow8) * K + sblk * 8;
  const u16* Bb = Bt + (size_t)(n0 + srow8) * K + sblk * 8;

#define SA_(bufd, h, j, kt) __builtin_amdgcn_global_load_lds(              \
    (as1cv)(Ab + ((h) * 128 + (j) * 64) * K + (kt) * 64),                  \
    (as3v)(&As[bufd][(h) * 128 + (j) * 64 + wave * 8][0]), 16, 0, 0)
#define SB_(bufd, h, j, kt) __builtin_amdgcn_global_load_lds(              \
    (as1cv)(Bb + ((h) * 128 + (j) * 64) * K + (kt) * 64),                  \
    (as3v)(&Bs[bufd][(h) * 128 + (j) * 64 + wave * 8][0]), 16, 0, 0)
#define LDA_(mf, ks) (*(const bf16x8*)&As[buf][wr * 128 + (mf) * 16 + l16] \
                                         [(((ks) * 4 + quad) ^ rsw) * 8])
#define LDB_(nf, ks) (*(const bf16x8*)&Bs[buf][wc * 64 + (nf) * 16 + l16]  \
                                         [(((ks) * 4 + quad) ^ rsw) * 8])

  // prologue: tile0 {B0,B1,A0,A1} then tile1 {B0,B1,A0}; drain to 3 ht.
  SB_(0, 0, 0, 0); SB_(0, 0, 1, 0); SB_(0, 1, 0, 0); SB_(0, 1, 1, 0);
  SA_(0, 0, 0, 0); SA_(0, 0, 1, 0); SA_(0, 1, 0, 0); SA_(0, 1, 1, 0);
  SB_(1, 0, 0, 1); SB_(1, 0, 1, 1); SB_(1, 1, 0, 1); SB_(1, 1, 1, 1);
  SA_(1, 0, 0, 1); SA_(1, 0, 1, 1);
  asm volatile("s_waitcnt vmcnt(6)" ::: "memory");
  __builtin_amdgcn_s_barrier();

  f32x4 acc[8][4] = {};

#pragma unroll 2
  for (int t = 0; t < NT; ++t) {
    const int buf = t & 1;
    bf16x8 bfr[4][2], a01[2][2], a23[2][2], a47[4][2];

    // ---- phase 0: read all B + A m0-1; stage (t+1) A1 (other buffer) ----
#pragma unroll
    for (int nf = 0; nf < 4; nf++) { bfr[nf][0] = LDB_(nf, 0); bfr[nf][1] = LDB_(nf, 1); }
#pragma unroll
    for (int mf = 0; mf < 2; mf++) { a01[mf][0] = LDA_(mf, 0); a01[mf][1] = LDA_(mf, 1); }
    if (t + 1 < NT) { SA_(buf ^ 1, 1, 0, t + 1); SA_(buf ^ 1, 1, 1, t + 1); }
    __builtin_amdgcn_s_barrier();
    asm volatile("s_waitcnt lgkmcnt(0)" ::: "memory");
    __builtin_amdgcn_s_setprio(1);
#pragma unroll
    for (int mf = 0; mf < 2; mf++)
#pragma unroll
      for (int nf = 0; nf < 4; nf++) {
        acc[mf][nf] = __builtin_amdgcn_mfma_f32_16x16x32_bf16(a01[mf][0], bfr[nf][0], acc[mf][nf], 0, 0, 0);
        acc[mf][nf] = __builtin_amdgcn_mfma_f32_16x16x32_bf16(a01[mf][1], bfr[nf][1], acc[mf][nf], 0, 0, 0);
      }
    __builtin_amdgcn_s_setprio(0);
    __builtin_amdgcn_s_barrier();

    // ---- phase 1: read A m2-3; stage (t+2) B0 ----
#pragma unroll
    for (int mf = 0; mf < 2; mf++) { a23[mf][0] = LDA_(2 + mf, 0); a23[mf][1] = LDA_(2 + mf, 1); }
    if (t + 2 < NT) { SB_(buf, 0, 0, t + 2); SB_(buf, 0, 1, t + 2); }
    __builtin_amdgcn_s_barrier();
    asm volatile("s_waitcnt lgkmcnt(0)" ::: "memory");
    __builtin_amdgcn_s_setprio(1);
#pragma unroll
    for (int mf = 0; mf < 2; mf++)
#pragma unroll
      for (int nf = 0; nf < 4; nf++) {
        acc[2 + mf][nf] = __builtin_amdgcn_mfma_f32_16x16x32_bf16(a23[mf][0], bfr[nf][0], acc[2 + mf][nf], 0, 0, 0);
        acc[2 + mf][nf] = __builtin_amdgcn_mfma_f32_16x16x32_bf16(a23[mf][1], bfr[nf][1], acc[2 + mf][nf], 0, 0, 0);
      }
    __builtin_amdgcn_s_setprio(0);
    __builtin_amdgcn_s_barrier();

    // ---- phase 2: read A m4-7; stage (t+2) B1 ----
#pragma unroll
    for (int mf = 0; mf < 4; mf++) { a47[mf][0] = LDA_(4 + mf, 0); a47[mf][1] = LDA_(4 + mf, 1); }
    if (t + 2 < NT) { SB_(buf, 1, 0, t + 2); SB_(buf, 1, 1, t + 2); }
    __builtin_amdgcn_s_barrier();
    asm volatile("s_waitcnt lgkmcnt(0)" ::: "memory");
    __builtin_amdgcn_s_setprio(1);
#pragma unroll
    for (int mf = 0; mf < 2; mf++)
#pragma unroll
      for (int nf = 0; nf < 4; nf++) {
        acc[4 + mf][nf] = __builtin_amdgcn_mfma_f32_16x16x32_bf16(a47[mf][0], bfr[nf][0], acc[4 + mf][nf], 0, 0, 0);
        acc[4 + mf][nf] = __builtin_amdgcn_mfma_f32_16x16x32_bf16(a47[mf][1], bfr[nf][1], acc[4 + mf][nf], 0, 0, 0);
      }
    __builtin_amdgcn_s_setprio(0);
    __builtin_amdgcn_s_barrier();

    // ---- phase 3: no reads; stage (t+2) A0; MFMA m6-7; counted vmcnt ----
    if (t + 2 < NT) { SA_(buf, 0, 0, t + 2); SA_(buf, 0, 1, t + 2); }
    __builtin_amdgcn_s_barrier();
    __builtin_amdgcn_s_setprio(1);
#pragma unroll
    for (int mf = 0; mf < 2; mf++)
#pragma unroll
      for (int nf = 0; nf < 4; nf++) {
        acc[6 + mf][nf] = __builtin_amdgcn_mfma_f32_16x16x32_bf16(a47[2 + mf][0], bfr[nf][0], acc[6 + mf][nf], 0, 0, 0);
        acc[6 + mf][nf] = __builtin_amdgcn_mfma_f32_16x16x32_bf16(a47[2 + mf][1], bfr[nf][1], acc[6 + mf][nf], 0, 0, 0);
      }
    __builtin_amdgcn_s_setprio(0);
    if (t < NT - 2) asm volatile("s_waitcnt vmcnt(6)" ::: "memory");
    else            asm volatile("s_waitcnt vmcnt(0)" ::: "memory");
    __builtin_amdgcn_s_barrier();
  }
#undef SA_
#undef SB_
#undef LDA_
#undef LDB_

  // epilogue: C/D layout col=lane&15, row=quad*4+reg. Q/K/V segment is
  // block-uniform (n0 multiple of 256, segments multiples of 1024).
  const int b = m0 >> 11;
  const int tb = (m0 & 2047) + wr * 128 + quad * 4;
  const int seg = n0 >> 10;
  if (seg == 0) {           // ---- Q, pre-scaled by 1/sqrt(d)*log2(e) ----
#pragma unroll
    for (int nf = 0; nf < 4; nf++) {
      int nn = n0 + wc * 64 + nf * 16 + l16;
      int hh = (nn & 1023) >> 6, dd = nn & 63;
      float bv = bias[nn];
      u16* base = qb + ((size_t)(b * HH + hh) * TT) * DD + dd;
#pragma unroll
      for (int mf = 0; mf < 8; mf++)
#pragma unroll
        for (int r = 0; r < 4; r++)
          base[(size_t)(tb + mf * 16 + r) * DD] =
              f2bf((acc[mf][nf][r] + bv) * 0.1803368801111f);
    }
  } else if (seg == 1) {    // ---- K ----
#pragma unroll
    for (int nf = 0; nf < 4; nf++) {
      int nn = n0 + wc * 64 + nf * 16 + l16;
      int hh = (nn & 1023) >> 6, dd = nn & 63;
      float bv = bias[nn];
      u16* base = kb + ((size_t)(b * HH + hh) * TT) * DD + dd;
#pragma unroll
      for (int mf = 0; mf < 8; mf++)
#pragma unroll
        for (int r = 0; r < 4; r++)
          base[(size_t)(tb + mf * 16 + r) * DD] = f2bf(acc[mf][nf][r] + bv);
    }
  } else {                  // ---- V, stored transposed [B,H,D,T] ----
#pragma unroll
    for (int nf = 0; nf < 4; nf++) {
      int nn = n0 + wc * 64 + nf * 16 + l16;
      int hh = (nn & 1023) >> 6, dd = nn & 63;
      float bv = bias[nn];
      u16* base = vt + ((size_t)(b * HH + hh) * DD + dd) * TT + tb;
#pragma unroll
      for (int mf = 0; mf < 8; mf++) {
        ushort4 st;
        st.x = f2bf(acc[mf][nf][0] + bv);
        st.y = f2bf(acc[mf][nf][1] + bv);
        st.z = f2bf(acc[mf][nf][2] + bv);
        st.w = f2bf(acc[mf][nf][3] + bv);
        *(ushort4*)(base + mf * 16) = st;
      }
    }
  }
}

// ---------------- GEMM: C[M][N] = A[M][K](bf16) * Bt[N][K]^T + bias --------
// (kept for the proj GEMM, mode 1; QKV now uses gemm_qkv256)
__global__ __launch_bounds__(256) void gemm_bt(
    const u16* __restrict__ A, const u16* __restrict__ Bt,
    const float* __restrict__ bias,
    int M, int N, int K, int mode,
    u16* __restrict__ qb, u16* __restrict__ kb, u16* __restrict__ vt,
    float* __restrict__ outf) {
  __shared__ u16 As[128][64];   // 16 KB
  __shared__ u16 Bs[128][64];   // 16 KB
  const int tid = threadIdx.x;
  const int lane = tid & 63, wave = tid >> 6;
  const int quad = lane >> 4, l16 = lane & 15;
  const int wy = wave >> 1, wx = wave & 1;  // 2x2 waves, 64x64 each
  const int m0 = blockIdx.x * 128, n0 = blockIdx.y * 128;
  const int srow = lane >> 3, sblk = (lane & 7) ^ (lane >> 3);  // row&7==srow
  const int rsw = l16 & 7;  // read-side swizzle

  f32x4 acc[4][4] = {};

  for (int k0 = 0; k0 < K; k0 += 64) {
#pragma unroll
    for (int i = 0; i < 4; i++) {
      int lr = wave * 32 + i * 8;          // lds row base (mult of 8)
      int row = lr + srow;
      __builtin_amdgcn_global_load_lds(
          (as1cv)(A + (size_t)(m0 + row) * K + k0 + sblk * 8),
          (as3v)(&As[lr][0]), 16, 0, 0);
      __builtin_amdgcn_global_load_lds(
          (as1cv)(Bt + (size_t)(n0 + row) * K + k0 + sblk * 8),
          (as3v)(&Bs[lr][0]), 16, 0, 0);
    }
    __syncthreads();
#pragma unroll
    for (int ks = 0; ks < 2; ks++) {
      const int pcol = ((ks * 4 + quad) ^ rsw) * 8;
      bf16x8 af[4], bfr[4];
#pragma unroll
      for (int i = 0; i < 4; i++)
        af[i] = *(const bf16x8*)&As[wy * 64 + i * 16 + l16][pcol];
#pragma unroll
      for (int j = 0; j < 4; j++)
        bfr[j] = *(const bf16x8*)&Bs[wx * 64 + j * 16 + l16][pcol];
#pragma unroll
      for (int i = 0; i < 4; i++)
#pragma unroll
        for (int j = 0; j < 4; j++)
          acc[i][j] = __builtin_amdgcn_mfma_f32_16x16x32_bf16(af[i], bfr[j], acc[i][j], 0, 0, 0);
    }
    __syncthreads();
  }

  // epilogue: C/D layout col=lane&15, row=quad*4+reg. Branch is block-uniform.
  if (mode == 1) {
#pragma unroll
    for (int i = 0; i < 4; i++)
#pragma unroll
      for (int j = 0; j < 4; j++) {
        int nn = n0 + wx * 64 + j * 16 + l16;
        float bv = bias[nn];
#pragma unroll
        for (int r = 0; r < 4; r++) {
          int mm = m0 + wy * 64 + i * 16 + quad * 4 + r;
          outf[(size_t)mm * N + nn] = acc[i][j][r] + bv;
        }
      }
  } else {
    const int b = m0 >> 11;                       // batch (block-uniform)
    const int tb = (m0 & 2047) + wy * 64 + quad * 4;
    if (n0 < 1024) {        // ---- Q, pre-scaled by 1/sqrt(d)*log2(e) ----
#pragma unroll
      for (int j = 0; j < 4; j++) {
        int nn = n0 + wx * 64 + j * 16 + l16;
        int h = nn >> 6, dd = nn & 63;
        float bv = bias[nn];
        u16* base = qb + ((size_t)(b * HH + h) * TT) * DD + dd;
#pragma unroll
        for (int i = 0; i < 4; i++)
#pragma unroll
          for (int r = 0; r < 4; r++)
            base[(size_t)(tb + i * 16 + r) * DD] =
                f2bf((acc[i][j][r] + bv) * 0.1803368801111f);
      }
    } else if (n0 < 2048) { // ---- K ----
#pragma unroll
      for (int j = 0; j < 4; j++) {
        int nn = n0 + wx * 64 + j * 16 + l16;
        int rem = nn & 1023, h = rem >> 6, dd = rem & 63;
        float bv = bias[nn];
        u16* base = kb + ((size_t)(b * HH + h) * TT) * DD + dd;
#pragma unroll
        for (int i = 0; i < 4; i++)
#pragma unroll
          for (int r = 0; r < 4; r++)
            base[(size_t)(tb + i * 16 + r) * DD] = f2bf(acc[i][j][r] + bv);
      }
    } else {                // ---- V, stored transposed [B,H,D,T] ----
#pragma unroll
      for (int j = 0; j < 4; j++) {
        int nn = n0 + wx * 64 + j * 16 + l16;
        int rem = nn & 1023, h = rem >> 6, dd = rem & 63;
        float bv = bias[nn];
        u16* base = vt + ((size_t)(b * HH + h) * DD + dd) * TT;
#pragma unroll
        for (int i = 0; i < 4; i++)
#pragma unroll
          for (int r = 0; r < 4; r++)
            base[tb + i * 16 + r] = f2bf(acc[i][j][r] + bv);
      }
    }
  }
}

// ---------------- flash attention (block-cooperative, S^T/O^T) -------------
// grid (bh=64, tile=16); block = 4 waves = 128 q rows. kv rounds of 128 =
// two proven 64-kv halves per barrier pair; V read per-c from LDS (no
// register hoist -> no spill). Linear block id === bh (mod 8) -> XCD L2.
__global__ __launch_bounds__(256, 3) void attn_kernel(
    const u16* __restrict__ q_buf, const u16* __restrict__ k_buf,
    const u16* __restrict__ v_t, u16* __restrict__ attn_out) {
  __shared__ __align__(16) u16 Ks[2][64][64];   // K  [kv][d]   16 KB
  __shared__ __align__(16) u16 Vs[2][64][64];   // V^T [d][kv]  16 KB
  __shared__ __align__(16) u16 Pl[4][16][64];   // per-wave P [q][kv] 8 KB
  const int tid = threadIdx.x;
  const int lane = tid & 63, wave = tid >> 6;
  const int quad = lane >> 4, l16 = lane & 15;
  const int bh = blockIdx.x;
  const int b = bh >> 4, h = bh & 15;
  const int tile = 15 - (int)blockIdx.y;        // heavy tiles dispatch first
  const int qt0 = tile * 128;
  const int qw = qt0 + wave * 32;               // wave's first q row
  const u16* Q = q_buf + (size_t)bh * TT * DD;
  const u16* Kp = k_buf + (size_t)bh * TT * DD;
  const u16* Vt = v_t + (size_t)bh * DD * TT;

  // staging geometry: lane -> (row group l>>3, 16B blk (l&7)^(l>>3))
  const int srow = lane >> 3;
  const int sblk = (lane & 7) ^ srow;
  const int swz = l16 & 7;                      // fragment-read swizzle

  bf16x8 qf[2][2];
#pragma unroll
  for (int f = 0; f < 2; f++)
#pragma unroll
    for (int h2 = 0; h2 < 2; h2++)
      qf[f][h2] = *(const bf16x8*)(Q + (size_t)(qw + f * 16 + l16) * DD + h2 * 32 + quad * 8);

  f32x4 o[2][4] = {};   // O^T[d = g*16+quad*4+r][q = l16]
  float l_p[2] = {0.f, 0.f};

  const int my_end = qw + 32;
  const int kv_stop = qt0 + 128;
  for (int kv0 = 0; kv0 < kv_stop; kv0 += 128) {
    // ---- stage both 64-kv halves: K rows and V^T cols ----
#pragma unroll
    for (int hh = 0; hh < 2; hh++)
#pragma unroll
      for (int i = 0; i < 2; i++) {
        int r = wave * 16 + i * 8 + srow;       // lds row 0..63 (row&7==srow)
        __builtin_amdgcn_global_load_lds(
            (as1cv)(Kp + (size_t)(kv0 + hh * 64 + r) * DD + sblk * 8),
            (as3v)(&Ks[hh][wave * 16 + i * 8][0]), 16, 0, 0);
        __builtin_amdgcn_global_load_lds(
            (as1cv)(Vt + (size_t)r * TT + kv0 + hh * 64 + sblk * 8),
            (as3v)(&Vs[hh][wave * 16 + i * 8][0]), 16, 0, 0);
      }
    __syncthreads();

#pragma unroll
    for (int hh = 0; hh < 2; hh++) {
      const int kb0 = kv0 + hh * 64;
      if (kb0 < my_end) {                       // wave-uniform causal skip
        const bool edge = (kb0 + 63 > qw);
        // ---- S^T = K * Q^T ----
        f32x4 s[2][4] = {};
#pragma unroll
        for (int kg = 0; kg < 4; kg++) {
          bf16x8 ka = *(const bf16x8*)&Ks[hh][kg * 16 + l16][(quad ^ swz) * 8];
          bf16x8 kb2 = *(const bf16x8*)&Ks[hh][kg * 16 + l16][((4 + quad) ^ swz) * 8];
#pragma unroll
          for (int f = 0; f < 2; f++) {
            s[f][kg] = __builtin_amdgcn_mfma_f32_16x16x32_bf16(ka, qf[f][0], s[f][kg], 0, 0, 0);
            s[f][kg] = __builtin_amdgcn_mfma_f32_16x16x32_bf16(kb2, qf[f][1], s[f][kg], 0, 0, 0);
          }
        }
        // ---- softmax (fixed-max exp2) + P store + PV ----
#pragma unroll
        for (int f = 0; f < 2; f++) {
          const int qi = qw + f * 16 + l16;
#pragma unroll
          for (int kg = 0; kg < 4; kg++) {
            float v0 = s[f][kg][0], v1 = s[f][kg][1], v2 = s[f][kg][2], v3 = s[f][kg][3];
            if (edge) {
              int kvb = kb0 + kg * 16 + quad * 4;
              v0 = (kvb + 0 <= qi) ? v0 : -1e30f;
              v1 = (kvb + 1 <= qi) ? v1 : -1e30f;
              v2 = (kvb + 2 <= qi) ? v2 : -1e30f;
              v3 = (kvb + 3 <= qi) ? v3 : -1e30f;
            }
            float e0 = __builtin_amdgcn_exp2f(v0);
            float e1 = __builtin_amdgcn_exp2f(v1);
            float e2 = __builtin_amdgcn_exp2f(v2);
            float e3 = __builtin_amdgcn_exp2f(v3);
            l_p[f] += (e0 + e1) + (e2 + e3);
            uint2 pk;
            pk.x = pack2(e0, e1);
            pk.y = pack2(e2, e3);
            // P[q=l16][kv]: 16B blk = kg*2+(quad>>1), swizzled; 8B half = quad&1
            *(uint2*)&Pl[wave][l16][((kg * 2 + (quad >> 1)) ^ swz) * 8 + (quad & 1) * 4] = pk;
          }
          __threadfence_block();                // same-wave DS write->read order
#pragma unroll
          for (int c = 0; c < 2; c++) {
            bf16x8 pa = *(const bf16x8*)&Pl[wave][l16][((c * 4 + quad) ^ swz) * 8];
#pragma unroll
            for (int g = 0; g < 4; g++) {
              bf16x8 vr = *(const bf16x8*)&Vs[hh][g * 16 + l16][((c * 4 + quad) ^ swz) * 8];
              o[f][g] = __builtin_amdgcn_mfma_f32_16x16x32_bf16(vr, pa, o[f][g], 0, 0, 0);
            }
          }
        }
      }
    }
    __syncthreads();
  }

  // epilogue: reduce l across quads, scale, vectorized store
#pragma unroll
  for (int f = 0; f < 2; f++) {
    float l = l_p[f];
    l += __shfl_xor(l, 16);
    l += __shfl_xor(l, 32);
    float inv_l = 1.0f / l;
    int trow = qw + f * 16 + l16;
#pragma unroll
    for (int g = 0; g < 4; g++) {
      ushort4 st;
      st.x = f2bf(o[f][g][0] * inv_l);
      st.y = f2bf(o[f][g][1] * inv_l);
      st.z = f2bf(o[f][g][2] * inv_l);
      st.w = f2bf(o[f][g][3] * inv_l);
      *(ushort4*)(attn_out + ((size_t)(b * TT + trow)) * CC + h * DD + g * 16 + quad * 4) = st;
    }
  }
}

extern "C" void kernel_launch(void* const* d_in, const int* in_sizes, int n_in,
                              void* d_out, int out_size, void* d_ws, size_t ws_size,
                              hipStream_t stream) {
  const float* x = (const float*)d_in[0];
  const float* w_qkv = (const float*)d_in[1];
  const float* b_qkv = (const float*)d_in[2];
  const float* w_proj = (const float*)d_in[3];
  const float* b_proj = (const float*)d_in[4];
  float* out = (float*)d_out;
  char* ws = (char*)d_ws;

  // workspace layout (72 MB total); xb aliases ao (xb dead before attn runs)
  u16* wqkvT = (u16*)(ws);                    // 3072*1024*2 = 6291456
  u16* wprojT = (u16*)(ws + 6291456);         // 1024*1024*2 = 2097152
  u16* qb = (u16*)(ws + 8388608);             // [B,H,T,D] bf16, 16 MB
  u16* kb = (u16*)(ws + 25165824);            // [B,H,T,D] bf16, 16 MB
  u16* vt = (u16*)(ws + 41943040);            // [B,H,D,T] bf16, 16 MB
  u16* ao = (u16*)(ws + 58720256);            // [B,T,C]   bf16, 16 MB
  u16* xb = ao;                               // x cast to bf16 (aliased)

  cast_f32_bf16<<<dim3(8192), 256, 0, stream>>>(x, xb);
  transpose_cast<<<dim3(96, 32), 256, 0, stream>>>(w_qkv, wqkvT, 1024, 3072);
  transpose_cast<<<dim3(32, 32), 256, 0, stream>>>(w_proj, wprojT, 1024, 1024);
  gemm_qkv256<<<dim3(384), 512, 0, stream>>>(xb, wqkvT, b_qkv, qb, kb, vt);
  attn_kernel<<<dim3(64, 16), 256, 0, stream>>>(qb, kb, vt, ao);
  gemm_bt<<<dim3(64, 8), 256, 0, stream>>>(ao, wprojT, b_proj, 8192, 1024, 1024, 1,
                                           nullptr, nullptr, nullptr, out);
}

// Round 2
// 246.223 us; speedup vs baseline: 1.0035x; 1.0035x over previous
//
#include <hip/hip_runtime.h>
#include <hip/hip_bf16.h>

// MHA: B=4 T=2048 C=1024 H=16 D=64, fp32 in/out, bf16 MFMA internally.
// R10: R9 post-mortem — 256x256 4-phase kernel ran at 6000cy/iter (4x the
//      schedule's cost model). Theory: compiler-inserted s_waitcnt vmcnt(0)
//      before each phase's C++ LDS reads (may-alias with global_load_lds
//      destinations) drains the whole prefetch queue every phase, defeating
//      the counted vmcnt(6). Fix: inline-asm ds_read_b128 for all fragment
//      reads (opaque to the waitcnt legalizer) + sched_barrier(0) after each
//      lgkmcnt(0) (rule #18 — compiler can no longer see MFMA->read dep).
//      Stage/read schedule, vmcnt placement, grid, epilogue unchanged.

typedef unsigned short u16;
typedef __bf16 bf16_t;
typedef bf16_t bf16x8 __attribute__((ext_vector_type(8)));
typedef float f32x4 __attribute__((ext_vector_type(4)));
typedef unsigned int u32x4 __attribute__((ext_vector_type(4)));
typedef u16 u16x8 __attribute__((ext_vector_type(8)));
typedef const __attribute__((address_space(1))) void* as1cv;
typedef __attribute__((address_space(3))) void* as3v;
typedef const __attribute__((address_space(3))) u16* as3cu16;

#define BB 4
#define TT 2048
#define CC 1024
#define HH 16
#define DD 64

static __device__ __forceinline__ u16 f2bf(float f) {
  union { float f; unsigned int u; } x; x.f = f;
  unsigned int u = x.u;
  u += 0x7fff + ((u >> 16) & 1);   // round-to-nearest-even
  return (u16)(u >> 16);
}

// pack two f32 -> two bf16 (truncation) in one v_perm_b32
static __device__ __forceinline__ unsigned int pack2(float lo, float hi) {
  return __builtin_amdgcn_perm(__float_as_uint(hi), __float_as_uint(lo),
                               0x07060302u);
}

// LDS read opaque to the compiler's waitcnt/alias machinery; ordering vs
// staging is enforced by our explicit s_waitcnt + s_barrier schedule.
static __device__ __forceinline__ bf16x8 ds_read128(as3cu16 p) {
  u32x4 r;
  asm volatile("ds_read_b128 %0, %1" : "=v"(r) : "v"((unsigned)(size_t)p));
  return __builtin_bit_cast(bf16x8, r);
}

// ---------------- fp32 -> bf16 row cast (x) --------------------------------
__global__ __launch_bounds__(256) void cast_f32_bf16(
    const float* __restrict__ in, u16* __restrict__ out) {
  int i = (blockIdx.x * 256 + threadIdx.x) * 4;
  float4 v = *(const float4*)(in + i);
  ushort4 o;
  o.x = f2bf(v.x); o.y = f2bf(v.y); o.z = f2bf(v.z); o.w = f2bf(v.w);
  *(ushort4*)(out + i) = o;
}

// ---------------- transpose + cast fp32[K][N] -> bf16[N][K] ----------------
__global__ __launch_bounds__(256) void transpose_cast(
    const float* __restrict__ in, u16* __restrict__ out, int K, int N) {
  __shared__ float tile[32][33];
  int n0 = blockIdx.x * 32, k0 = blockIdx.y * 32;
  int tx = threadIdx.x & 31, ty = threadIdx.x >> 5;  // 32 x 8
#pragma unroll
  for (int i = 0; i < 32; i += 8)
    tile[ty + i][tx] = in[(size_t)(k0 + ty + i) * N + n0 + tx];
  __syncthreads();
#pragma unroll
  for (int i = 0; i < 32; i += 8)
    out[(size_t)(n0 + ty + i) * K + k0 + tx] = f2bf(tile[tx][ty + i]);
}

// ---------------- QKV GEMM: 256x256 tile, 8 waves, 4-phase K-loop ----------
// C[8192][3072] = A[8192][1024] * Bt[3072][1024]^T, scattered to q/k/vt.
// LDS: 2 x (A 256x64 + B 256x64) bf16 = 128 KiB. Swizzle: 16B slot =
// blk ^ (row & 7) (pre-swizzled global source, linear gload_lds dest).
__global__ __launch_bounds__(512, 2) void gemm_qkv256(
    const u16* __restrict__ A, const u16* __restrict__ Bt,
    const float* __restrict__ bias,
    u16* __restrict__ qb, u16* __restrict__ kb, u16* __restrict__ vt) {
  constexpr int K = 1024;
  constexpr int NT = 16;                     // K / 64
  __shared__ u16 As[2][256][64];             // 64 KB
  __shared__ u16 Bs[2][256][64];             // 64 KB
  const int tid = threadIdx.x;
  const int lane = tid & 63, wave = tid >> 6;
  const int quad = lane >> 4, l16 = lane & 15;
  const int wr = wave >> 2, wc = wave & 3;   // 2x4 waves, 128x64 out each
  const int rsw = l16 & 7;                   // fragment-read swizzle
  const int srow8 = tid >> 3;                // 0..63: row in 64-row stripe
  const int sblk = (lane & 7) ^ (lane >> 3); // pre-swizzled source blk

  // XCD-aware chunking: 384 blocks -> 8 chunks of 48 = 8mi x 6ni rects
  const int id = blockIdx.x;
  const int ch = id & 7, w = id >> 3;
  const int mi = (ch & 3) * 8 + w / 6;
  const int ni = (ch >> 2) * 6 + w % 6;
  const int m0 = mi * 256, n0 = ni * 256;

  const u16* Ab = A + (size_t)(m0 + srow8) * K + sblk * 8;
  const u16* Bb = Bt + (size_t)(n0 + srow8) * K + sblk * 8;

#define SA_(bufd, h, j, kt) __builtin_amdgcn_global_load_lds(              \
    (as1cv)(Ab + ((h) * 128 + (j) * 64) * K + (kt) * 64),                  \
    (as3v)(&As[bufd][(h) * 128 + (j) * 64 + wave * 8][0]), 16, 0, 0)
#define SB_(bufd, h, j, kt) __builtin_amdgcn_global_load_lds(              \
    (as1cv)(Bb + ((h) * 128 + (j) * 64) * K + (kt) * 64),                  \
    (as3v)(&Bs[bufd][(h) * 128 + (j) * 64 + wave * 8][0]), 16, 0, 0)
#define LDA_(mf, ks) ds_read128((as3cu16)&As[buf][wr * 128 + (mf) * 16 + l16] \
                                               [(((ks) * 4 + quad) ^ rsw) * 8])
#define LDB_(nf, ks) ds_read128((as3cu16)&Bs[buf][wc * 64 + (nf) * 16 + l16]  \
                                               [(((ks) * 4 + quad) ^ rsw) * 8])

  // prologue: tile0 {B0,B1,A0,A1} then tile1 {B0,B1,A0}; drain to 3 ht.
  SB_(0, 0, 0, 0); SB_(0, 0, 1, 0); SB_(0, 1, 0, 0); SB_(0, 1, 1, 0);
  SA_(0, 0, 0, 0); SA_(0, 0, 1, 0); SA_(0, 1, 0, 0); SA_(0, 1, 1, 0);
  SB_(1, 0, 0, 1); SB_(1, 0, 1, 1); SB_(1, 1, 0, 1); SB_(1, 1, 1, 1);
  SA_(1, 0, 0, 1); SA_(1, 0, 1, 1);
  asm volatile("s_waitcnt vmcnt(6)" ::: "memory");
  __builtin_amdgcn_s_barrier();

  f32x4 acc[8][4] = {};

#pragma unroll 2
  for (int t = 0; t < NT; ++t) {
    const int buf = t & 1;
    bf16x8 bfr[4][2], a01[2][2], a23[2][2], a47[4][2];

    // ---- phase 0: read all B + A m0-1; stage (t+1) A1 (other buffer) ----
#pragma unroll
    for (int nf = 0; nf < 4; nf++) { bfr[nf][0] = LDB_(nf, 0); bfr[nf][1] = LDB_(nf, 1); }
#pragma unroll
    for (int mf = 0; mf < 2; mf++) { a01[mf][0] = LDA_(mf, 0); a01[mf][1] = LDA_(mf, 1); }
    if (t + 1 < NT) { SA_(buf ^ 1, 1, 0, t + 1); SA_(buf ^ 1, 1, 1, t + 1); }
    __builtin_amdgcn_s_barrier();
    asm volatile("s_waitcnt lgkmcnt(0)" ::: "memory");
    __builtin_amdgcn_sched_barrier(0);
    __builtin_amdgcn_s_setprio(1);
#pragma unroll
    for (int mf = 0; mf < 2; mf++)
#pragma unroll
      for (int nf = 0; nf < 4; nf++) {
        acc[mf][nf] = __builtin_amdgcn_mfma_f32_16x16x32_bf16(a01[mf][0], bfr[nf][0], acc[mf][nf], 0, 0, 0);
        acc[mf][nf] = __builtin_amdgcn_mfma_f32_16x16x32_bf16(a01[mf][1], bfr[nf][1], acc[mf][nf], 0, 0, 0);
      }
    __builtin_amdgcn_s_setprio(0);
    __builtin_amdgcn_s_barrier();

    // ---- phase 1: read A m2-3; stage (t+2) B0 ----
#pragma unroll
    for (int mf = 0; mf < 2; mf++) { a23[mf][0] = LDA_(2 + mf, 0); a23[mf][1] = LDA_(2 + mf, 1); }
    if (t + 2 < NT) { SB_(buf, 0, 0, t + 2); SB_(buf, 0, 1, t + 2); }
    __builtin_amdgcn_s_barrier();
    asm volatile("s_waitcnt lgkmcnt(0)" ::: "memory");
    __builtin_amdgcn_sched_barrier(0);
    __builtin_amdgcn_s_setprio(1);
#pragma unroll
    for (int mf = 0; mf < 2; mf++)
#pragma unroll
      for (int nf = 0; nf < 4; nf++) {
        acc[2 + mf][nf] = __builtin_amdgcn_mfma_f32_16x16x32_bf16(a23[mf][0], bfr[nf][0], acc[2 + mf][nf], 0, 0, 0);
        acc[2 + mf][nf] = __builtin_amdgcn_mfma_f32_16x16x32_bf16(a23[mf][1], bfr[nf][1], acc[2 + mf][nf], 0, 0, 0);
      }
    __builtin_amdgcn_s_setprio(0);
    __builtin_amdgcn_s_barrier();

    // ---- phase 2: read A m4-7; stage (t+2) B1 ----
#pragma unroll
    for (int mf = 0; mf < 4; mf++) { a47[mf][0] = LDA_(4 + mf, 0); a47[mf][1] = LDA_(4 + mf, 1); }
    if (t + 2 < NT) { SB_(buf, 1, 0, t + 2); SB_(buf, 1, 1, t + 2); }
    __builtin_amdgcn_s_barrier();
    asm volatile("s_waitcnt lgkmcnt(0)" ::: "memory");
    __builtin_amdgcn_sched_barrier(0);
    __builtin_amdgcn_s_setprio(1);
#pragma unroll
    for (int mf = 0; mf < 2; mf++)
#pragma unroll
      for (int nf = 0; nf < 4; nf++) {
        acc[4 + mf][nf] = __builtin_amdgcn_mfma_f32_16x16x32_bf16(a47[mf][0], bfr[nf][0], acc[4 + mf][nf], 0, 0, 0);
        acc[4 + mf][nf] = __builtin_amdgcn_mfma_f32_16x16x32_bf16(a47[mf][1], bfr[nf][1], acc[4 + mf][nf], 0, 0, 0);
      }
    __builtin_amdgcn_s_setprio(0);
    __builtin_amdgcn_s_barrier();

    // ---- phase 3: no reads; stage (t+2) A0; MFMA m6-7; counted vmcnt ----
    if (t + 2 < NT) { SA_(buf, 0, 0, t + 2); SA_(buf, 0, 1, t + 2); }
    __builtin_amdgcn_s_barrier();
    __builtin_amdgcn_s_setprio(1);
#pragma unroll
    for (int mf = 0; mf < 2; mf++)
#pragma unroll
      for (int nf = 0; nf < 4; nf++) {
        acc[6 + mf][nf] = __builtin_amdgcn_mfma_f32_16x16x32_bf16(a47[2 + mf][0], bfr[nf][0], acc[6 + mf][nf], 0, 0, 0);
        acc[6 + mf][nf] = __builtin_amdgcn_mfma_f32_16x16x32_bf16(a47[2 + mf][1], bfr[nf][1], acc[6 + mf][nf], 0, 0, 0);
      }
    __builtin_amdgcn_s_setprio(0);
    if (t < NT - 2) asm volatile("s_waitcnt vmcnt(6)" ::: "memory");
    else            asm volatile("s_waitcnt vmcnt(0)" ::: "memory");
    __builtin_amdgcn_s_barrier();
  }
#undef SA_
#undef SB_
#undef LDA_
#undef LDB_

  // epilogue: C/D layout col=lane&15, row=quad*4+reg. Q/K/V segment is
  // block-uniform (n0 multiple of 256, segments multiples of 1024).
  const int b = m0 >> 11;
  const int tb = (m0 & 2047) + wr * 128 + quad * 4;
  const int seg = n0 >> 10;
  if (seg == 0) {           // ---- Q, pre-scaled by 1/sqrt(d)*log2(e) ----
#pragma unroll
    for (int nf = 0; nf < 4; nf++) {
      int nn = n0 + wc * 64 + nf * 16 + l16;
      int hh = (nn & 1023) >> 6, dd = nn & 63;
      float bv = bias[nn];
      u16* base = qb + ((size_t)(b * HH + hh) * TT) * DD + dd;
#pragma unroll
      for (int mf = 0; mf < 8; mf++)
#pragma unroll
        for (int r = 0; r < 4; r++)
          base[(size_t)(tb + mf * 16 + r) * DD] =
              f2bf((acc[mf][nf][r] + bv) * 0.1803368801111f);
    }
  } else if (seg == 1) {    // ---- K ----
#pragma unroll
    for (int nf = 0; nf < 4; nf++) {
      int nn = n0 + wc * 64 + nf * 16 + l16;
      int hh = (nn & 1023) >> 6, dd = nn & 63;
      float bv = bias[nn];
      u16* base = kb + ((size_t)(b * HH + hh) * TT) * DD + dd;
#pragma unroll
      for (int mf = 0; mf < 8; mf++)
#pragma unroll
        for (int r = 0; r < 4; r++)
          base[(size_t)(tb + mf * 16 + r) * DD] = f2bf(acc[mf][nf][r] + bv);
    }
  } else {                  // ---- V, stored transposed [B,H,D,T] ----
#pragma unroll
    for (int nf = 0; nf < 4; nf++) {
      int nn = n0 + wc * 64 + nf * 16 + l16;
      int hh = (nn & 1023) >> 6, dd = nn & 63;
      float bv = bias[nn];
      u16* base = vt + ((size_t)(b * HH + hh) * DD + dd) * TT + tb;
#pragma unroll
      for (int mf = 0; mf < 8; mf++) {
        ushort4 st;
        st.x = f2bf(acc[mf][nf][0] + bv);
        st.y = f2bf(acc[mf][nf][1] + bv);
        st.z = f2bf(acc[mf][nf][2] + bv);
        st.w = f2bf(acc[mf][nf][3] + bv);
        *(ushort4*)(base + mf * 16) = st;
      }
    }
  }
}

// ---------------- GEMM: C[M][N] = A[M][K](bf16) * Bt[N][K]^T + bias --------
// (kept for the proj GEMM, mode 1; QKV now uses gemm_qkv256)
__global__ __launch_bounds__(256) void gemm_bt(
    const u16* __restrict__ A, const u16* __restrict__ Bt,
    const float* __restrict__ bias,
    int M, int N, int K, int mode,
    u16* __restrict__ qb, u16* __restrict__ kb, u16* __restrict__ vt,
    float* __restrict__ outf) {
  __shared__ u16 As[128][64];   // 16 KB
  __shared__ u16 Bs[128][64];   // 16 KB
  const int tid = threadIdx.x;
  const int lane = tid & 63, wave = tid >> 6;
  const int quad = lane >> 4, l16 = lane & 15;
  const int wy = wave >> 1, wx = wave & 1;  // 2x2 waves, 64x64 each
  const int m0 = blockIdx.x * 128, n0 = blockIdx.y * 128;
  const int srow = lane >> 3, sblk = (lane & 7) ^ (lane >> 3);  // row&7==srow
  const int rsw = l16 & 7;  // read-side swizzle

  f32x4 acc[4][4] = {};

  for (int k0 = 0; k0 < K; k0 += 64) {
#pragma unroll
    for (int i = 0; i < 4; i++) {
      int lr = wave * 32 + i * 8;          // lds row base (mult of 8)
      int row = lr + srow;
      __builtin_amdgcn_global_load_lds(
          (as1cv)(A + (size_t)(m0 + row) * K + k0 + sblk * 8),
          (as3v)(&As[lr][0]), 16, 0, 0);
      __builtin_amdgcn_global_load_lds(
          (as1cv)(Bt + (size_t)(n0 + row) * K + k0 + sblk * 8),
          (as3v)(&Bs[lr][0]), 16, 0, 0);
    }
    __syncthreads();
#pragma unroll
    for (int ks = 0; ks < 2; ks++) {
      const int pcol = ((ks * 4 + quad) ^ rsw) * 8;
      bf16x8 af[4], bfr[4];
#pragma unroll
      for (int i = 0; i < 4; i++)
        af[i] = *(const bf16x8*)&As[wy * 64 + i * 16 + l16][pcol];
#pragma unroll
      for (int j = 0; j < 4; j++)
        bfr[j] = *(const bf16x8*)&Bs[wx * 64 + j * 16 + l16][pcol];
#pragma unroll
      for (int i = 0; i < 4; i++)
#pragma unroll
        for (int j = 0; j < 4; j++)
          acc[i][j] = __builtin_amdgcn_mfma_f32_16x16x32_bf16(af[i], bfr[j], acc[i][j], 0, 0, 0);
    }
    __syncthreads();
  }

  // epilogue: C/D layout col=lane&15, row=quad*4+reg. Branch is block-uniform.
  if (mode == 1) {
#pragma unroll
    for (int i = 0; i < 4; i++)
#pragma unroll
      for (int j = 0; j < 4; j++) {
        int nn = n0 + wx * 64 + j * 16 + l16;
        float bv = bias[nn];
#pragma unroll
        for (int r = 0; r < 4; r++) {
          int mm = m0 + wy * 64 + i * 16 + quad * 4 + r;
          outf[(size_t)mm * N + nn] = acc[i][j][r] + bv;
        }
      }
  } else {
    const int b = m0 >> 11;                       // batch (block-uniform)
    const int tb = (m0 & 2047) + wy * 64 + quad * 4;
    if (n0 < 1024) {        // ---- Q, pre-scaled by 1/sqrt(d)*log2(e) ----
#pragma unroll
      for (int j = 0; j < 4; j++) {
        int nn = n0 + wx * 64 + j * 16 + l16;
        int h = nn >> 6, dd = nn & 63;
        float bv = bias[nn];
        u16* base = qb + ((size_t)(b * HH + h) * TT) * DD + dd;
#pragma unroll
        for (int i = 0; i < 4; i++)
#pragma unroll
          for (int r = 0; r < 4; r++)
            base[(size_t)(tb + i * 16 + r) * DD] =
                f2bf((acc[i][j][r] + bv) * 0.1803368801111f);
      }
    } else if (n0 < 2048) { // ---- K ----
#pragma unroll
      for (int j = 0; j < 4; j++) {
        int nn = n0 + wx * 64 + j * 16 + l16;
        int rem = nn & 1023, h = rem >> 6, dd = rem & 63;
        float bv = bias[nn];
        u16* base = kb + ((size_t)(b * HH + h) * TT) * DD + dd;
#pragma unroll
        for (int i = 0; i < 4; i++)
#pragma unroll
          for (int r = 0; r < 4; r++)
            base[(size_t)(tb + i * 16 + r) * DD] = f2bf(acc[i][j][r] + bv);
      }
    } else {                // ---- V, stored transposed [B,H,D,T] ----
#pragma unroll
      for (int j = 0; j < 4; j++) {
        int nn = n0 + wx * 64 + j * 16 + l16;
        int rem = nn & 1023, h = rem >> 6, dd = rem & 63;
        float bv = bias[nn];
        u16* base = vt + ((size_t)(b * HH + h) * DD + dd) * TT;
#pragma unroll
        for (int i = 0; i < 4; i++)
#pragma unroll
          for (int r = 0; r < 4; r++)
            base[tb + i * 16 + r] = f2bf(acc[i][j][r] + bv);
      }
    }
  }
}

// ---------------- flash attention (block-cooperative, S^T/O^T) -------------
// grid (bh=64, tile=16); block = 4 waves = 128 q rows. kv rounds of 128 =
// two proven 64-kv halves per barrier pair; V read per-c from LDS (no
// register hoist -> no spill). Linear block id === bh (mod 8) -> XCD L2.
__global__ __launch_bounds__(256, 3) void attn_kernel(
    const u16* __restrict__ q_buf, const u16* __restrict__ k_buf,
    const u16* __restrict__ v_t, u16* __restrict__ attn_out) {
  __shared__ __align__(16) u16 Ks[2][64][64];   // K  [kv][d]   16 KB
  __shared__ __align__(16) u16 Vs[2][64][64];   // V^T [d][kv]  16 KB
  __shared__ __align__(16) u16 Pl[4][16][64];   // per-wave P [q][kv] 8 KB
  const int tid = threadIdx.x;
  const int lane = tid & 63, wave = tid >> 6;
  const int quad = lane >> 4, l16 = lane & 15;
  const int bh = blockIdx.x;
  const int b = bh >> 4, h = bh & 15;
  const int tile = 15 - (int)blockIdx.y;        // heavy tiles dispatch first
  const int qt0 = tile * 128;
  const int qw = qt0 + wave * 32;               // wave's first q row
  const u16* Q = q_buf + (size_t)bh * TT * DD;
  const u16* Kp = k_buf + (size_t)bh * TT * DD;
  const u16* Vt = v_t + (size_t)bh * DD * TT;

  // staging geometry: lane -> (row group l>>3, 16B blk (l&7)^(l>>3))
  const int srow = lane >> 3;
  const int sblk = (lane & 7) ^ srow;
  const int swz = l16 & 7;                      // fragment-read swizzle

  bf16x8 qf[2][2];
#pragma unroll
  for (int f = 0; f < 2; f++)
#pragma unroll
    for (int h2 = 0; h2 < 2; h2++)
      qf[f][h2] = *(const bf16x8*)(Q + (size_t)(qw + f * 16 + l16) * DD + h2 * 32 + quad * 8);

  f32x4 o[2][4] = {};   // O^T[d = g*16+quad*4+r][q = l16]
  float l_p[2] = {0.f, 0.f};

  const int my_end = qw + 32;
  const int kv_stop = qt0 + 128;
  for (int kv0 = 0; kv0 < kv_stop; kv0 += 128) {
    // ---- stage both 64-kv halves: K rows and V^T cols ----
#pragma unroll
    for (int hh = 0; hh < 2; hh++)
#pragma unroll
      for (int i = 0; i < 2; i++) {
        int r = wave * 16 + i * 8 + srow;       // lds row 0..63 (row&7==srow)
        __builtin_amdgcn_global_load_lds(
            (as1cv)(Kp + (size_t)(kv0 + hh * 64 + r) * DD + sblk * 8),
            (as3v)(&Ks[hh][wave * 16 + i * 8][0]), 16, 0, 0);
        __builtin_amdgcn_global_load_lds(
            (as1cv)(Vt + (size_t)r * TT + kv0 + hh * 64 + sblk * 8),
            (as3v)(&Vs[hh][wave * 16 + i * 8][0]), 16, 0, 0);
      }
    __syncthreads();

#pragma unroll
    for (int hh = 0; hh < 2; hh++) {
      const int kb0 = kv0 + hh * 64;
      if (kb0 < my_end) {                       // wave-uniform causal skip
        const bool edge = (kb0 + 63 > qw);
        // ---- S^T = K * Q^T ----
        f32x4 s[2][4] = {};
#pragma unroll
        for (int kg = 0; kg < 4; kg++) {
          bf16x8 ka = *(const bf16x8*)&Ks[hh][kg * 16 + l16][(quad ^ swz) * 8];
          bf16x8 kb2 = *(const bf16x8*)&Ks[hh][kg * 16 + l16][((4 + quad) ^ swz) * 8];
#pragma unroll
          for (int f = 0; f < 2; f++) {
            s[f][kg] = __builtin_amdgcn_mfma_f32_16x16x32_bf16(ka, qf[f][0], s[f][kg], 0, 0, 0);
            s[f][kg] = __builtin_amdgcn_mfma_f32_16x16x32_bf16(kb2, qf[f][1], s[f][kg], 0, 0, 0);
          }
        }
        // ---- softmax (fixed-max exp2) + P store + PV ----
#pragma unroll
        for (int f = 0; f < 2; f++) {
          const int qi = qw + f * 16 + l16;
#pragma unroll
          for (int kg = 0; kg < 4; kg++) {
            float v0 = s[f][kg][0], v1 = s[f][kg][1], v2 = s[f][kg][2], v3 = s[f][kg][3];
            if (edge) {
              int kvb = kb0 + kg * 16 + quad * 4;
              v0 = (kvb + 0 <= qi) ? v0 : -1e30f;
              v1 = (kvb + 1 <= qi) ? v1 : -1e30f;
              v2 = (kvb + 2 <= qi) ? v2 : -1e30f;
              v3 = (kvb + 3 <= qi) ? v3 : -1e30f;
            }
            float e0 = __builtin_amdgcn_exp2f(v0);
            float e1 = __builtin_amdgcn_exp2f(v1);
            float e2 = __builtin_amdgcn_exp2f(v2);
            float e3 = __builtin_amdgcn_exp2f(v3);
            l_p[f] += (e0 + e1) + (e2 + e3);
            uint2 pk;
            pk.x = pack2(e0, e1);
            pk.y = pack2(e2, e3);
            // P[q=l16][kv]: 16B blk = kg*2+(quad>>1), swizzled; 8B half = quad&1
            *(uint2*)&Pl[wave][l16][((kg * 2 + (quad >> 1)) ^ swz) * 8 + (quad & 1) * 4] = pk;
          }
          __threadfence_block();                // same-wave DS write->read order
#pragma unroll
          for (int c = 0; c < 2; c++) {
            bf16x8 pa = *(const bf16x8*)&Pl[wave][l16][((c * 4 + quad) ^ swz) * 8];
#pragma unroll
            for (int g = 0; g < 4; g++) {
              bf16x8 vr = *(const bf16x8*)&Vs[hh][g * 16 + l16][((c * 4 + quad) ^ swz) * 8];
              o[f][g] = __builtin_amdgcn_mfma_f32_16x16x32_bf16(vr, pa, o[f][g], 0, 0, 0);
            }
          }
        }
      }
    }
    __syncthreads();
  }

  // epilogue: reduce l across quads, scale, vectorized store
#pragma unroll
  for (int f = 0; f < 2; f++) {
    float l = l_p[f];
    l += __shfl_xor(l, 16);
    l += __shfl_xor(l, 32);
    float inv_l = 1.0f / l;
    int trow = qw + f * 16 + l16;
#pragma unroll
    for (int g = 0; g < 4; g++) {
      ushort4 st;
      st.x = f2bf(o[f][g][0] * inv_l);
      st.y = f2bf(o[f][g][1] * inv_l);
      st.z = f2bf(o[f][g][2] * inv_l);
      st.w = f2bf(o[f][g][3] * inv_l);
      *(ushort4*)(attn_out + ((size_t)(b * TT + trow)) * CC + h * DD + g * 16 + quad * 4) = st;
    }
  }
}

extern "C" void kernel_launch(void* const* d_in, const int* in_sizes, int n_in,
                              void* d_out, int out_size, void* d_ws, size_t ws_size,
                              hipStream_t stream) {
  const float* x = (const float*)d_in[0];
  const float* w_qkv = (const float*)d_in[1];
  const float* b_qkv = (const float*)d_in[2];
  const float* w_proj = (const float*)d_in[3];
  const float* b_proj = (const float*)d_in[4];
  float* out = (float*)d_out;
  char* ws = (char*)d_ws;

  // workspace layout (72 MB total); xb aliases ao (xb dead before attn runs)
  u16* wqkvT = (u16*)(ws);                    // 3072*1024*2 = 6291456
  u16* wprojT = (u16*)(ws + 6291456);         // 1024*1024*2 = 2097152
  u16* qb = (u16*)(ws + 8388608);             // [B,H,T,D] bf16, 16 MB
  u16* kb = (u16*)(ws + 25165824);            // [B,H,T,D] bf16, 16 MB
  u16* vt = (u16*)(ws + 41943040);            // [B,H,D,T] bf16, 16 MB
  u16* ao = (u16*)(ws + 58720256);            // [B,T,C]   bf16, 16 MB
  u16* xb = ao;                               // x cast to bf16 (aliased)

  cast_f32_bf16<<<dim3(8192), 256, 0, stream>>>(x, xb);
  transpose_cast<<<dim3(96, 32), 256, 0, stream>>>(w_qkv, wqkvT, 1024, 3072);
  transpose_cast<<<dim3(32, 32), 256, 0, stream>>>(w_proj, wprojT, 1024, 1024);
  gemm_qkv256<<<dim3(384), 512, 0, stream>>>(xb, wqkvT, b_qkv, qb, kb, vt);
  attn_kernel<<<dim3(64, 16), 256, 0, stream>>>(qb, kb, vt, ao);
  gemm_bt<<<dim3(64, 8), 256, 0, stream>>>(ao, wprojT, b_proj, 8192, 1024, 1024, 1,
                                           nullptr, nullptr, nullptr, out);
}